// Round 6
// baseline (130.637 us; speedup 1.0000x reference)
//
#include <hip/hip_runtime.h>
#include <hip/hip_fp16.h>

// QLinear with per-k fp16 requantized accumulation (mptorch fma semantics).
// out = q16( q16_scan_fma( q8(x) @ q8(W)^T ) + q8(b) )
// v_pk_fma_f16 (single RNE per fma) == reference fp32-mul/add/quant chain
// (fp32 add exact for |acc|<64; data max ~7).
// R6: R1/R4/R5 all ran at the DS-instruction-issue ceiling (2 DS insts/thread/k
// -> 16 wave-insts/CU/k ~= 130-160 cyc/k). This round cuts DS to 0.5 inst/
// thread/k: w stays [n][k] in LDS read as b128 k-runs (8 k per inst); x is
// streamed from global/L1 (wave needs only 4 unique 16-B lines per 8k) on the
// separate VMEM pipe. Register transpose of w via lows2/highs2half2; x k-half
// broadcast via pk_fma op_sel. No transposes in prep (pure elementwise quant).

#define M_DIM 2048
#define N_DIM 1024
#define K_DIM 1024

#define BM 64
#define BN 64
#define BK 64
#define WPAD 72   // LDS row stride in halfs: 144 B (16-B aligned, 2-way banks)
#define NCHUNK (K_DIM / BK)

// dst.lo = x.lo*w.lo+acc.lo ; dst.hi = x.lo*w.hi+acc.hi   (x.lo broadcast)
#define PKFMA_LO(acc, x, w) \
  asm("v_pk_fma_f16 %0, %1, %2, %0 op_sel:[0,0,0] op_sel_hi:[0,1,1]" \
      : "+v"(acc) : "v"(x), "v"(w))
// dst.lo = x.hi*w.lo+acc.lo ; dst.hi = x.hi*w.hi+acc.hi   (x.hi broadcast)
#define PKFMA_HI(acc, x, w) \
  asm("v_pk_fma_f16 %0, %1, %2, %0 op_sel:[1,0,0] op_sel_hi:[1,1,1]" \
      : "+v"(acc) : "v"(x), "v"(w))

__device__ __forceinline__ __half2 h2(unsigned u) {
  __half2 r; *reinterpret_cast<unsigned*>(&r) = u; return r;
}
__device__ __forceinline__ unsigned u32(__half2 h) {
  return *reinterpret_cast<unsigned*>(&h);
}

// exact E4M3 (exp=4, man=3) quantization of an fp32 value, result fp32
__device__ __forceinline__ float quant_e4m3(float v) {
  unsigned au = __float_as_uint(v) & 0x7fffffffu;
  if (au == 0u) return v;                 // +-0
  int e = (int)(au >> 23) - 127;          // floor(log2|v|) for normals
  if (e < -6) e = -6;                     // fp32 subnorms hit the clamp too
  float s  = __uint_as_float((unsigned)(130 - e) << 23);  // 2^(3-e), exact
  float is = __uint_as_float((unsigned)(124 + e) << 23);  // 2^(e-3), exact
  float r = rintf(v * s) * is;            // RNE (half-to-even), all steps exact
  return fminf(240.f, fmaxf(-240.f, r));
}

// Pure elementwise quant, same layout: blocks [0,2048) -> x, [2048,3072) -> w.
__global__ __launch_bounds__(256) void prep_kernel(const float* __restrict__ x,
                                                   const float* __restrict__ w,
                                                   __half* __restrict__ xq,
                                                   __half* __restrict__ wq) {
  const int bid = blockIdx.x;
  const float* src;
  __half* dst;
  size_t base;
  if (bid < 2048) { src = x; dst = xq; base = (size_t)bid * 1024; }
  else            { src = w; dst = wq; base = (size_t)(bid - 2048) * 1024; }
  const size_t idx = base + threadIdx.x * 4;
  const float4 v = *reinterpret_cast<const float4*>(src + idx);
  __half2 lo{__float2half(quant_e4m3(v.x)), __float2half(quant_e4m3(v.y))};
  __half2 hi{__float2half(quant_e4m3(v.z)), __float2half(quant_e4m3(v.w))};
  uint2 o{u32(lo), u32(hi)};
  *reinterpret_cast<uint2*>(dst + idx) = o;
}

// xq [M][K] fp16, wq [N][K] fp16, b [N] fp32 raw, out [M][N] fp32
__global__ __launch_bounds__(256) void gemm_qfma(const __half* __restrict__ xq,
                                                 const __half* __restrict__ wq,
                                                 const float* __restrict__ b,
                                                 float* __restrict__ outp) {
  __shared__ __half ws[2][BN][WPAD];  // 2 x 9 KB, w tile in [n][k] layout

  const int tid = threadIdx.x;
  const int tn = tid & 15;   // 16 n-threads * 4 = BN
  const int tm = tid >> 4;   // 16 m-threads * 4 = BM
  const int tm4 = tm * 4, tn4 = tn * 4;
  const int bn0 = blockIdx.x * BN;
  const int bm0 = blockIdx.y * BM;

  unsigned acc[4][2];  // acc[i][j] = half2 {C(m_i, n_{2j}), C(m_i, n_{2j+1})}
#pragma unroll
  for (int i = 0; i < 4; i++)
#pragma unroll
    for (int j = 0; j < 2; j++) acc[i][j] = 0u;

  // x row base pointers (rows tm4+0/1 off xb0, tm4+2/3 off xb1; +K_DIM = next row)
  const __half* xb0 = xq + (size_t)(bm0 + tm4) * K_DIM;
  const __half* xb1 = xq + (size_t)(bm0 + tm4 + 2) * K_DIM;

  // w staging: 256 threads cover 64 rows x 64 k in 2 passes of b128
  const int srow = tid >> 3;          // 0..31 (rows srow, srow+32)
  const int scol = (tid & 7) * 8;     // 0..56 halfs (16-B segments)

  uint4 gw[2];
#pragma unroll
  for (int p = 0; p < 2; p++)
    gw[p] = *reinterpret_cast<const uint4*>(wq + (size_t)(bn0 + srow + p * 32) * K_DIM + scol);

  uint4 xbuf[2][4], wbuf[2][4];

  for (int c = 0; c < NCHUNK; c++) {
    const int buf = c & 1;
    const int k0 = c * BK;
#pragma unroll
    for (int p = 0; p < 2; p++)
      *reinterpret_cast<uint4*>(&ws[buf][srow + p * 32][scol]) = gw[p];
    if (c + 1 < NCHUNK) {  // global prefetch of next w chunk during compute
#pragma unroll
      for (int p = 0; p < 2; p++)
        gw[p] = *reinterpret_cast<const uint4*>(
            wq + (size_t)(bn0 + srow + p * 32) * K_DIM + k0 + BK + scol);
    }
    // x sub-block 0 prefetch (global, independent of the barrier)
    xbuf[0][0] = *reinterpret_cast<const uint4*>(xb0 + k0);
    xbuf[0][1] = *reinterpret_cast<const uint4*>(xb0 + K_DIM + k0);
    xbuf[0][2] = *reinterpret_cast<const uint4*>(xb1 + k0);
    xbuf[0][3] = *reinterpret_cast<const uint4*>(xb1 + K_DIM + k0);

    __syncthreads();

    // w sub-block 0 preload from LDS
#pragma unroll
    for (int i = 0; i < 4; i++)
      wbuf[0][i] = *reinterpret_cast<const uint4*>(&ws[buf][tn4 + i][0]);

#pragma unroll
    for (int j = 0; j < 8; j++) {        // 8 sub-blocks of 8 k
      const int cur = j & 1, nxt = cur ^ 1;
      if (j < 7) {                        // prefetch sub-block j+1
        const int kj = k0 + (j + 1) * 8;
        xbuf[nxt][0] = *reinterpret_cast<const uint4*>(xb0 + kj);
        xbuf[nxt][1] = *reinterpret_cast<const uint4*>(xb0 + K_DIM + kj);
        xbuf[nxt][2] = *reinterpret_cast<const uint4*>(xb1 + kj);
        xbuf[nxt][3] = *reinterpret_cast<const uint4*>(xb1 + K_DIM + kj);
#pragma unroll
        for (int i = 0; i < 4; i++)
          wbuf[nxt][i] = *reinterpret_cast<const uint4*>(&ws[buf][tn4 + i][(j + 1) * 8]);
      }
#pragma unroll
      for (int j2 = 0; j2 < 4; j2++) {   // dwords = k pairs (2j2, 2j2+1), ascending
        const unsigned A0 = (&wbuf[cur][0].x)[j2], B0 = (&wbuf[cur][1].x)[j2];
        const unsigned A1 = (&wbuf[cur][2].x)[j2], B1 = (&wbuf[cur][3].x)[j2];
        const unsigned we0 = u32(__lows2half2 (h2(A0), h2(B0)));  // {n0,n1}@k even
        const unsigned we1 = u32(__lows2half2 (h2(A1), h2(B1)));  // {n2,n3}@k even
        const unsigned wo0 = u32(__highs2half2(h2(A0), h2(B0)));  // {n0,n1}@k odd
        const unsigned wo1 = u32(__highs2half2(h2(A1), h2(B1)));  // {n2,n3}@k odd
        const unsigned x0 = (&xbuf[cur][0].x)[j2], x1 = (&xbuf[cur][1].x)[j2];
        const unsigned x2 = (&xbuf[cur][2].x)[j2], x3 = (&xbuf[cur][3].x)[j2];
        // k even (lo half of x dword), then k odd (hi half): ascending per acc
        PKFMA_LO(acc[0][0], x0, we0); PKFMA_LO(acc[0][1], x0, we1);
        PKFMA_LO(acc[1][0], x1, we0); PKFMA_LO(acc[1][1], x1, we1);
        PKFMA_LO(acc[2][0], x2, we0); PKFMA_LO(acc[2][1], x2, we1);
        PKFMA_LO(acc[3][0], x3, we0); PKFMA_LO(acc[3][1], x3, we1);
        PKFMA_HI(acc[0][0], x0, wo0); PKFMA_HI(acc[0][1], x0, wo1);
        PKFMA_HI(acc[1][0], x1, wo0); PKFMA_HI(acc[1][1], x1, wo1);
        PKFMA_HI(acc[2][0], x2, wo0); PKFMA_HI(acc[2][1], x2, wo1);
        PKFMA_HI(acc[3][0], x3, wo0); PKFMA_HI(acc[3][1], x3, wo1);
      }
    }
    __syncthreads();  // all reads of buf done before it is overwritten (c+2)
  }

  // epilogue: out = fp16RNE(acc + q8(b)), stored fp32 (fp32 add exact here)
  float4 bq = *reinterpret_cast<const float4*>(b + bn0 + tn4);
  bq.x = quant_e4m3(bq.x); bq.y = quant_e4m3(bq.y);
  bq.z = quant_e4m3(bq.z); bq.w = quant_e4m3(bq.w);
#pragma unroll
  for (int i = 0; i < 4; i++) {
    const __half2 h0 = h2(acc[i][0]);
    const __half2 h1 = h2(acc[i][1]);
    float4 o;
    o.x = __half2float(__float2half(__low2float(h0)  + bq.x));
    o.y = __half2float(__float2half(__high2float(h0) + bq.y));
    o.z = __half2float(__float2half(__low2float(h1)  + bq.z));
    o.w = __half2float(__float2half(__high2float(h1) + bq.w));
    *reinterpret_cast<float4*>(outp + (size_t)(bm0 + tm4 + i) * N_DIM + bn0 + tn4) = o;
  }
}

extern "C" void kernel_launch(void* const* d_in, const int* in_sizes, int n_in,
                              void* d_out, int out_size, void* d_ws, size_t ws_size,
                              hipStream_t stream) {
  const float* x = (const float*)d_in[0];   // [2048][1024]
  const float* w = (const float*)d_in[1];   // [1024][1024] (out_f, in_f)
  const float* b = (const float*)d_in[2];   // [1024]
  float* outp = (float*)d_out;              // [2048][1024] fp32

  char* ws = (char*)d_ws;
  __half* xq = (__half*)ws;                        // [M][K]  4 MiB
  __half* wq = (__half*)(ws + (size_t)(4 << 20));  // [N][K]  2 MiB

  hipLaunchKernelGGL(prep_kernel, dim3(3072), dim3(256), 0, stream,
                     x, w, xq, wq);
  hipLaunchKernelGGL(gemm_qfma, dim3(N_DIM / BN, M_DIM / BM), dim3(256), 0, stream,
                     xq, wq, b, outp);
}